// Round 4
// baseline (189.702 us; speedup 1.0000x reference)
//
#include <hip/hip_runtime.h>
#include <math.h>

#define KPOT 5
#define THREADS 256
#define TROWS 1024                        // rows per tile
#define XF (TROWS * 2)                    // 2048 floats (8 KB) x / noise per tile
#define GF (TROWS * KPOT)                 // 5120 floats (20 KB) gumbel per tile
#define NBLOCKS 512                       // persistent: 2 blocks/CU at 72 KB LDS

// global -> LDS async DMA, 16 B per lane (1024 B per wave-call).
// LDS dest must be wave-uniform; HW adds lane*16.
__device__ __forceinline__ void load_lds16(const float* gptr, float* lptr) {
    __builtin_amdgcn_global_load_lds(
        (const __attribute__((address_space(1))) void*)gptr,
        (__attribute__((address_space(3))) void*)lptr, 16, 0, 0);
}

// Persistent 2-phase DMA pipeline (T3 minimum-2-phase):
//   prologue: STAGE(buf0, tile0); drain; barrier
//   loop:     STAGE(buf^1, tile+stride)   <- queue refilled BEFORE compute
//             compute tile from buf (LDS reads, coalesced stores)
//             __syncthreads() (drain+barrier); swap
// DMA latency for tile i+1 hides under compute of tile i; the CU's memory
// queue never sits empty across block generations (only 512 launches).
__global__ __launch_bounds__(THREADS) void lightsb_kernel(
    const float* __restrict__ x,
    const float* __restrict__ r,
    const float* __restrict__ log_S,
    const float* __restrict__ log_alpha,
    const float* __restrict__ gumbel,
    const float* __restrict__ noise,
    float* __restrict__ out,
    int n_rows)
{
    __shared__ float xsh[2][XF];
    __shared__ float nsh[2][XF];
    __shared__ float gsh[2][GF];

    const int t    = threadIdx.x;
    const int w    = t >> 6;              // wave id 0..3
    const int lane = t & 63;
    const long long ntiles = n_rows / TROWS;
    const long long stride = gridDim.x;

    float S0[KPOT], S1[KPOT], r0[KPOT], r1[KPOT], la[KPOT], q0[KPOT], q1[KPOT];

#define STAGE(buf, tile)                                                        \
    do {                                                                        \
        const float* xg = x      + (tile) * (TROWS * 2);                        \
        const float* ng = noise  + (tile) * (TROWS * 2);                        \
        const float* gg = gumbel + (tile) * (TROWS * KPOT);                     \
        _Pragma("unroll")                                                       \
        for (int j = 0; j < 2; ++j) {                                           \
            const int c = w + 4 * j;                                            \
            load_lds16(xg + c * 256 + lane * 4, &xsh[buf][c * 256]);            \
            load_lds16(ng + c * 256 + lane * 4, &nsh[buf][c * 256]);            \
        }                                                                       \
        _Pragma("unroll")                                                       \
        for (int j = 0; j < 5; ++j) {                                           \
            const int c = w + 4 * j;                                            \
            load_lds16(gg + c * 256 + lane * 4, &gsh[buf][c * 256]);            \
        }                                                                       \
    } while (0)

    long long tile = blockIdx.x;
    if (tile < ntiles) STAGE(0, tile);

    // per-k constants (uniform, cached) overlap the first STAGE
#pragma unroll
    for (int k = 0; k < KPOT; ++k) {
        float s0 = expf(log_S[2 * k + 0]);
        float s1 = expf(log_S[2 * k + 1]);
        S0[k] = s0;  S1[k] = s1;
        r0[k] = r[2 * k + 0];  r1[k] = r[2 * k + 1];
        la[k] = log_alpha[k];
        q0[k] = sqrtf(s0);  q1[k] = sqrtf(s1);           // EPS = 1.0
    }

    __syncthreads();                      // drains prologue DMA (vmcnt(0)+barrier)

    int cur = 0;
    for (; tile < ntiles; tile += stride) {
        const long long nxt = tile + stride;
        if (nxt < ntiles) STAGE(cur ^ 1, nxt);           // refill queue FIRST

        // ---- compute current tile from LDS ----
        const float4* xs4 = reinterpret_cast<const float4*>(xsh[cur]);
        const float4* ns4 = reinterpret_cast<const float4*>(nsh[cur]);
        const float*  gs  = gsh[cur];
        float4* o4 = reinterpret_cast<float4*>(out) + tile * (TROWS / 2);

#pragma unroll
        for (int p = 0; p < 2; ++p) {
            const float4 xv = xs4[p * 256 + t];          // rows p*512+2t, +1
            const float4 nv = ns4[p * 256 + t];
            const float* g0 = &gs[(p * 512 + 2 * t) * KPOT];
            float ov[4];

#pragma unroll
            for (int h = 0; h < 2; ++h) {
                const float xx0 = (h == 0) ? xv.x : xv.z;
                const float xx1 = (h == 0) ? xv.y : xv.w;
                const float nn0 = (h == 0) ? nv.x : nv.z;
                const float nn1 = (h == 0) ? nv.y : nv.w;
                const float* g = g0 + h * KPOT;

                const float u0 = 0.5f * xx0 * xx0;
                const float u1 = 0.5f * xx1 * xx1;

                float best = fmaf(S0[0], u0, fmaf(S1[0], u1,
                             fmaf(r0[0], xx0, fmaf(r1[0], xx1, la[0] + g[0]))));
                float bS0 = S0[0], bS1 = S1[0];
                float br0 = r0[0], br1 = r1[0];
                float bq0 = q0[0], bq1 = q1[0];
#pragma unroll
                for (int k = 1; k < KPOT; ++k) {
                    float s = fmaf(S0[k], u0, fmaf(S1[k], u1,
                              fmaf(r0[k], xx0, fmaf(r1[k], xx1, la[k] + g[k]))));
                    bool c = s > best;     // strict > keeps first max (jnp.argmax)
                    best = c ? s : best;
                    bS0 = c ? S0[k] : bS0;
                    bS1 = c ? S1[k] : bS1;
                    br0 = c ? r0[k] : br0;
                    br1 = c ? r1[k] : br1;
                    bq0 = c ? q0[k] : bq0;
                    bq1 = c ? q1[k] : bq1;
                }
                ov[2 * h + 0] = fmaf(bS0, xx0, fmaf(bq0, nn0, br0));
                ov[2 * h + 1] = fmaf(bS1, xx1, fmaf(bq1, nn1, br1));
            }
            o4[p * 256 + t] = make_float4(ov[0], ov[1], ov[2], ov[3]);
        }

        __syncthreads();                  // drain next-tile DMA + publish buffer
        cur ^= 1;
    }

    // ---- scalar tail for n_rows % TROWS != 0 (grid-stride across all blocks) ----
    for (long long row = ntiles * TROWS + (long long)blockIdx.x * THREADS + t;
         row < n_rows; row += stride * THREADS) {
        float x0 = x[row * 2 + 0];
        float x1 = x[row * 2 + 1];
        float u0 = 0.5f * x0 * x0;
        float u1 = 0.5f * x1 * x1;
        float best = fmaf(S0[0], u0, fmaf(S1[0], u1,
                     fmaf(r0[0], x0, fmaf(r1[0], x1, la[0] + gumbel[row * KPOT + 0]))));
        int bidx = 0;
#pragma unroll
        for (int k = 1; k < KPOT; ++k) {
            float s = fmaf(S0[k], u0, fmaf(S1[k], u1,
                      fmaf(r0[k], x0, fmaf(r1[k], x1, la[k] + gumbel[row * KPOT + k]))));
            if (s > best) { best = s; bidx = k; }
        }
        float n0 = noise[row * 2 + 0];
        float n1 = noise[row * 2 + 1];
        out[row * 2 + 0] = fmaf(S0[bidx], x0, fmaf(q0[bidx], n0, r0[bidx]));
        out[row * 2 + 1] = fmaf(S1[bidx], x1, fmaf(q1[bidx], n1, r1[bidx]));
    }
#undef STAGE
}

extern "C" void kernel_launch(void* const* d_in, const int* in_sizes, int n_in,
                              void* d_out, int out_size, void* d_ws, size_t ws_size,
                              hipStream_t stream) {
    const float* x         = (const float*)d_in[0];
    const float* r         = (const float*)d_in[1];
    const float* log_S     = (const float*)d_in[2];
    const float* log_alpha = (const float*)d_in[3];
    const float* gumbel    = (const float*)d_in[4];
    const float* noise     = (const float*)d_in[5];
    float* out = (float*)d_out;

    const int n_rows = in_sizes[0] / 2;                      // DIM = 2
    const long long ntiles = n_rows / TROWS;
    int grid = (int)((ntiles < NBLOCKS) ? (ntiles > 0 ? ntiles : 1) : NBLOCKS);

    lightsb_kernel<<<grid, THREADS, 0, stream>>>(x, r, log_S, log_alpha,
                                                 gumbel, noise, out, n_rows);
}